// Round 6
// baseline (345.167 us; speedup 1.0000x reference)
//
#include <hip/hip_runtime.h>
#include <cmath>

typedef short bf16x8 __attribute__((ext_vector_type(8)));
typedef float f32x4 __attribute__((ext_vector_type(4)));
typedef unsigned short us8v __attribute__((ext_vector_type(8)));

#define T_DIM 1024

__device__ __forceinline__ unsigned short rtn_bf16(float f) {
    unsigned u = __float_as_uint(f);
    return (unsigned short)((u + 0x7FFFu + ((u >> 16) & 1u)) >> 16);
}
// Truncation-based exact 3-limb split (subtracting a truncation is exact in fp32)
__device__ __forceinline__ void split3(float f, unsigned short& h1,
                                       unsigned short& h2, unsigned short& h3) {
    unsigned u = __float_as_uint(f);
    h1 = (unsigned short)(u >> 16);
    float r1 = f - __uint_as_float(u & 0xFFFF0000u);
    unsigned u1 = __float_as_uint(r1);
    h2 = (unsigned short)(u1 >> 16);
    float r2 = r1 - __uint_as_float(u1 & 0xFFFF0000u);
    h3 = rtn_bf16(r2);
}

// split 8 floats -> 3 limb us8v and store at swizzled LDS offset
__device__ __forceinline__ void split_store8(const float4& a, const float4& b,
                                             unsigned short* __restrict__ A0,
                                             unsigned short* __restrict__ A1,
                                             unsigned short* __restrict__ A2,
                                             int off) {
    const float fv[8] = {a.x, a.y, a.z, a.w, b.x, b.y, b.z, b.w};
    us8v o1, o2, o3;
    #pragma unroll
    for (int i = 0; i < 8; ++i) {
        unsigned short h1, h2, h3;
        split3(fv[i], h1, h2, h3);
        o1[i] = h1; o2[i] = h2; o3[i] = h3;
    }
    *(us8v*)&A0[off] = o1;
    *(us8v*)&A1[off] = o2;
    *(us8v*)&A2[off] = o3;
}

// ---------------------------------------------------------------------------
// Software grid barrier (persistent-grid pattern). Safe on CDNA4 because:
//  - each wave's __syncthreads pre-drain (vmcnt(0)) puts its stores in the
//    XCD L2; the RELEASE-scoped atomic add writes back L2 to the device
//    coherence point; the ACQUIRE-scoped poll invalidates L1/L2 before any
//    post-barrier read.
//  - residency of all 512 blocks is guaranteed by __launch_bounds__(256,2)
//    (<=256 unified VGPR -> >=2 blocks/CU) and 48 KiB LDS (3 blocks/CU).
// Counters live in d_ws and are hipMemsetAsync-zeroed each launch.
// ---------------------------------------------------------------------------
__device__ __forceinline__ void grid_bar(unsigned* __restrict__ ctr,
                                         unsigned target, bool wait) {
    __syncthreads();
    if (threadIdx.x == 0) {
        __hip_atomic_fetch_add(ctr, 1u, __ATOMIC_ACQ_REL, __HIP_MEMORY_SCOPE_AGENT);
        if (wait) {
            while (__hip_atomic_load(ctr, __ATOMIC_ACQUIRE,
                                     __HIP_MEMORY_SCOPE_AGENT) < target)
                __builtin_amdgcn_s_sleep(4);
        }
    }
    __syncthreads();
}

// ---------------------------------------------------------------------------
// GEMM job: EXACT copy of the R1 kernel body (measured 77-81 us standalone)
// with (bm, bn) as parameters. Double-buffered LDS, one barrier per K-step.
// Limb values, MFMA product order (a1w1,a1w2,a2w1,a2w2,a1w3,a3w1), kt/nt
// order and epilogue identical -> bit-identical xbuf.
// ---------------------------------------------------------------------------
__device__ __forceinline__ void gemm_job(const float* __restrict__ in,
                                         const unsigned short* __restrict__ wT1,
                                         const unsigned short* __restrict__ wT2,
                                         const unsigned short* __restrict__ wT3,
                                         float* __restrict__ xbuf,
                                         unsigned short (* __restrict__ As)[3][128 * 32],
                                         int bm, int bn, int tid) {
    const int wave = tid >> 6;
    const int lane = tid & 63;
    const int l15  = lane & 15;
    const int quad = lane >> 4;
    const int wm   = (wave >> 1) * 64;
    const int wn   = (wave & 1) * 64;

    f32x4 acc[4][4];
    #pragma unroll
    for (int i = 0; i < 4; ++i)
        #pragma unroll
        for (int j = 0; j < 4; ++j) acc[i][j] = (f32x4){0.f, 0.f, 0.f, 0.f};

    const int r  = tid >> 1;               // staging row 0..127
    const int hf = tid & 1;                // staging k-half (16 floats)
    const int rx = r & 3;                  // XOR swizzle key (4 chunks/row)
    const int off0 = r * 32 + (((hf << 1) | 0) ^ rx) * 8;
    const int off1 = r * 32 + (((hf << 1) | 1) ^ rx) * 8;
    const float* arow = in + (size_t)(bm * 128 + r) * 256 + hf * 16;

    // ---- prologue: tile 0 -> buf0; load tile-1 floats ----
    float4 av0[4];
    #pragma unroll
    for (int j = 0; j < 4; ++j) av0[j] = *(const float4*)(arow + j * 4);
    float4 avn[4];                          // holds data for tile kt+1
    #pragma unroll
    for (int j = 0; j < 4; ++j) avn[j] = *(const float4*)(arow + 32 + j * 4);
    split_store8(av0[0], av0[1], &As[0][0][0], &As[0][1][0], &As[0][2][0], off0);
    split_store8(av0[2], av0[3], &As[0][0][0], &As[0][1][0], &As[0][2][0], off1);
    __syncthreads();

    #pragma unroll
    for (int kt = 0; kt < 8; ++kt) {
        const int cur = kt & 1;

        // 1) A fragments for tile kt
        bf16x8 af[3][4];
        #pragma unroll
        for (int mt = 0; mt < 4; ++mt) {
            const int m  = wm + mt * 16 + l15;
            const int ro = m * 32 + ((quad ^ (m & 3)) * 8);
            af[0][mt] = *(const bf16x8*)&As[cur][0][ro];
            af[1][mt] = *(const bf16x8*)&As[cur][1][ro];
            af[2][mt] = *(const bf16x8*)&As[cur][2][ro];
        }

        // 2) split tile kt+1 into the other buffer
        if (kt < 7) {
            split_store8(avn[0], avn[1], &As[cur ^ 1][0][0], &As[cur ^ 1][1][0],
                         &As[cur ^ 1][2][0], off0);
            split_store8(avn[2], avn[3], &As[cur ^ 1][0][0], &As[cur ^ 1][1][0],
                         &As[cur ^ 1][2][0], off1);
        }

        // 3) single barrier per K-step
        __syncthreads();

        // 4) prefetch tile kt+2 raw floats: latency hides under MFMA phase
        if (kt < 6) {
            const float* ap = arow + (kt + 2) * 32;
            #pragma unroll
            for (int j = 0; j < 4; ++j) avn[j] = *(const float4*)(ap + j * 4);
        }

        // 5) MFMA phase, B pipelined one nt ahead
        const int k0 = kt * 32;
        size_t wo = (size_t)(bn * 128 + wn + l15) * 256 + k0 + quad * 8;
        bf16x8 b1 = *(const bf16x8*)(wT1 + wo);
        bf16x8 b2 = *(const bf16x8*)(wT2 + wo);
        bf16x8 b3 = *(const bf16x8*)(wT3 + wo);

        #pragma unroll
        for (int nt = 0; nt < 4; ++nt) {
            bf16x8 n1, n2, n3;
            if (nt < 3) {
                const size_t won = wo + (size_t)16 * 256;   // next ncol = +16
                n1 = *(const bf16x8*)(wT1 + won);
                n2 = *(const bf16x8*)(wT2 + won);
                n3 = *(const bf16x8*)(wT3 + won);
            }
            #pragma unroll
            for (int mt = 0; mt < 4; ++mt) {
                f32x4 a = acc[mt][nt];
                a = __builtin_amdgcn_mfma_f32_16x16x32_bf16(af[0][mt], b1, a, 0, 0, 0);
                a = __builtin_amdgcn_mfma_f32_16x16x32_bf16(af[0][mt], b2, a, 0, 0, 0);
                a = __builtin_amdgcn_mfma_f32_16x16x32_bf16(af[1][mt], b1, a, 0, 0, 0);
                a = __builtin_amdgcn_mfma_f32_16x16x32_bf16(af[1][mt], b2, a, 0, 0, 0);
                a = __builtin_amdgcn_mfma_f32_16x16x32_bf16(af[0][mt], b3, a, 0, 0, 0);
                a = __builtin_amdgcn_mfma_f32_16x16x32_bf16(af[2][mt], b1, a, 0, 0, 0);
                acc[mt][nt] = a;
            }
            if (nt < 3) { b1 = n1; b2 = n2; b3 = n3; wo += (size_t)16 * 256; }
        }
    }

    // epilogue: C/D layout col=lane&15, row=quad*4+reg
    #pragma unroll
    for (int mt = 0; mt < 4; ++mt) {
        #pragma unroll
        for (int nt = 0; nt < 4; ++nt) {
            const int C  = bn * 128 + wn + nt * 16 + l15;
            const int Rb = bm * 128 + wm + mt * 16 + quad * 4;
            #pragma unroll
            for (int reg = 0; reg < 4; ++reg)
                xbuf[(size_t)(Rb + reg) * 256 + C] = acc[mt][nt][reg];
        }
    }
}

// ---------------------------------------------------------------------------
// SINGLE kernel (plain launch, graph-capture-safe): wsplit -> grid_bar ->
// GEMM (2 bn jobs) -> grid_bar -> scan. Launch-count 3 -> 1 saves ~70 us of
// measured per-launch overhead (~35 us/launch fit across R0-R4).
// R5's cooperative launch never executed (capture/validation rejection);
// this replaces grid.sync with an explicit release/acquire counter barrier.
// __launch_bounds__(256,2): <=256 unified VGPR -> 2 blocks/CU guaranteed ->
// all 512 blocks co-resident -> barrier cannot deadlock.
// Phases are the measured bodies verbatim -> bit-identical output.
// ---------------------------------------------------------------------------
__global__ __launch_bounds__(256, 2) void lif_all(const float* __restrict__ in,
                                                  const float* __restrict__ w,
                                                  unsigned short* __restrict__ wT1,
                                                  unsigned short* __restrict__ wT2,
                                                  unsigned short* __restrict__ wT3,
                                                  float* __restrict__ xbuf,
                                                  float* __restrict__ U,
                                                  unsigned* __restrict__ bars,
                                                  double dcy_syn, double dcy_mem,
                                                  double scl_mem) {
    __shared__ unsigned short As[2][3][128 * 32];   // 48 KiB, GEMM phase

    const int tid = threadIdx.x;
    const int blk = blockIdx.x;

    // ---- phase 0: wsplit (blocks 0..255, one element per thread) ----
    if (blk < 256) {
        const int gid = blk * 256 + tid;
        const int k = gid >> 8, n = gid & 255;
        unsigned short h1, h2, h3;
        split3(w[gid], h1, h2, h3);
        const int o = n * 256 + k;
        wT1[o] = h1; wT2[o] = h2; wT3[o] = h3;
    }
    grid_bar(&bars[0], 512, true);

    // ---- phase 1: GEMM, two bn jobs per block (bm = blk) ----
    gemm_job(in, wT1, wT2, wT3, xbuf, As, blk, 0, tid);
    __syncthreads();   // LDS reuse hazard between jobs
    gemm_job(in, wT1, wT2, wT3, xbuf, As, blk, 1, tid);
    grid_bar(&bars[1], 512, blk < 256);   // non-scanning blocks just arrive

    // ---- phase 2: LIF scan (blocks 0..255, wave 0; R0 body, ~5 us) ----
    if (blk < 256 && tid < 64) {
        const int b = blk >> 2;
        const int o = (blk & 3) * 64 + tid;

        const float* xp = xbuf + (size_t)b * T_DIM * 256 + o;
        float* up = U + (size_t)b * T_DIM * 256 + o;

        up[0] = 0.0f;                      // U[b][0][o] = initial state
        double syn = 0.0, mem = 0.0;

        float bufA[32], bufB[32];
        #pragma unroll
        for (int j = 0; j < 32; ++j)
            bufA[j] = __builtin_nontemporal_load(xp + (size_t)j * 256);

        #pragma unroll 1
        for (int bt = 0; bt < 16; ++bt) {  // 16 x (2 batches of 32) = 1024 steps
            const int tb = bt * 64;
            // phase A: prefetch next batch into B, consume A
            {
                const float* np = xp + (size_t)(tb + 32) * 256;
                #pragma unroll
                for (int j = 0; j < 32; ++j)
                    bufB[j] = __builtin_nontemporal_load(np + (size_t)j * 256);
            }
            #pragma unroll
            for (int j = 0; j < 32; ++j) {
                const int t = tb + j;
                double nm = dcy_mem * mem + scl_mem * syn;
                if (mem - 1.0 > 0.0) nm = 0.0;
                syn = dcy_syn * syn + (double)bufA[j];
                mem = nm;
                __builtin_nontemporal_store((float)mem, up + (size_t)(t + 1) * 256);
            }
            // phase B: prefetch next batch into A (guard last), consume B
            if (bt < 15) {
                const float* np = xp + (size_t)(tb + 64) * 256;
                #pragma unroll
                for (int j = 0; j < 32; ++j)
                    bufA[j] = __builtin_nontemporal_load(np + (size_t)j * 256);
            }
            #pragma unroll
            for (int j = 0; j < 32; ++j) {
                const int t = tb + 32 + j;
                double nm = dcy_mem * mem + scl_mem * syn;
                if (mem - 1.0 > 0.0) nm = 0.0;
                syn = dcy_syn * syn + (double)bufB[j];
                mem = nm;
                if (t < T_DIM - 1)         // skip only the final t=1023 store
                    __builtin_nontemporal_store((float)mem, up + (size_t)(t + 1) * 256);
            }
        }
    }
}

extern "C" void kernel_launch(void* const* d_in, const int* in_sizes, int n_in,
                              void* d_out, int out_size, void* d_ws, size_t ws_size,
                              hipStream_t stream) {
    const float* in = (const float*)d_in[0];   // fp32 [64][1024][256]
    const float* w  = (const float*)d_in[1];   // fp32 [256][256]
    float* U = (float*)d_out;                  // fp32 [64][1024][256]

    const double dcy_mem = exp(-0.001 / (0.01  + 1e-16));
    const double dcy_syn = exp(-0.001 / (0.005 + 1e-16));
    const double scl_mem = 1.0 - dcy_mem;

    // ws layout: wT1|wT2|wT3 (3 x 128 KiB bf16) | barrier counters (in the
    // 384K..512K gap) | xbuf (64 MiB fp32 at 512K)
    char* ws = (char*)d_ws;
    unsigned short* wT1 = (unsigned short*)ws;
    unsigned short* wT2 = (unsigned short*)(ws + 131072);
    unsigned short* wT3 = (unsigned short*)(ws + 262144);
    unsigned* bars      = (unsigned*)(ws + 393216);
    float* xbuf = (float*)(ws + 524288);

    hipMemsetAsync(bars, 0, 256, stream);   // reset barrier counters (captured)
    lif_all<<<dim3(512), dim3(256), 0, stream>>>(in, w, wT1, wT2, wT3, xbuf, U,
                                                 bars, dcy_syn, dcy_mem, scl_mem);
}